// Round 15
// baseline (48.158 us; speedup 1.0000x reference)
//
#include <hip/hip_runtime.h>

// Conv2D 3x3 VALID NHWC, B=16 H=W=224 C=32 F=32 -> [16,222,222,32] fp32.
// Round 15: R14 (wave-autonomous strips, no barriers) = 45.6us best. Its
// stage pipeline is only 1 row deep: SLOAD(r+3) issued and CONSUMED (vmcnt
// drain for SWRITE) within the same iteration -> HBM latency partially
// exposed every row with only 2 waves/SIMD to cover it.
// This round: depth-2 via TWO named stage register sets (svA/svB, static
// parity, manual x2 unroll): iter r = SLOAD(r+4)->set(r%2) | compute(r) |
// SWRITE(r+3)<-set((r+1)%2). Load-to-use distance ~2 compute phases >> HBM
// latency. Ring-of-4 WAR checked: write slot (r+3)&3 = (r-1)&3, consumed.
// +36 VGPR -> launch_bounds(512,1) (LDS 135KB = 1 block/CU anyway).

#define HO 222
#define WO 222
#define HIN 224
#define WIN 224
#define CIN 32
#define FOUT 32

#define RPW 7                 // output rows per wave-strip
#define WROWB 4224            // 66 px * 64 B bf16 (unpadded -- conflict-free)
#define WAVELDS 16896         // 4 ring slots
#define NSG 9                 // stage granule-iters per lane

typedef __attribute__((ext_vector_type(8))) short short8;
typedef __attribute__((ext_vector_type(4))) float float4v;

__device__ inline short f2bf(float f) {                  // RNE (weights only)
    unsigned u = __builtin_bit_cast(unsigned, f);
    unsigned r = (u + 0x7FFFu + ((u >> 16) & 1u)) >> 16;
    return (short)r;
}

__global__ __launch_bounds__(512, 1) void conv3x3_wave(
    const float* __restrict__ x,     // [16,224,224,32]
    const float* __restrict__ w,     // [32][288 = (kh,kw,c)]
    const float* __restrict__ bias,  // [32]
    float* __restrict__ out)         // [16,222,222,32]
{
    __shared__ uint4 lds_all[8 * WAVELDS / 16];          // 135168 B
    const int tid  = threadIdx.x;
    const int lane = tid & 63;
    const int wave = tid >> 6;                           // 0..7
    char* wbase = reinterpret_cast<char*>(lds_all) + wave * WAVELDS;

    const int fcol = lane & 15;            // A row (filter) / D col (pixel)
    const int kq   = lane >> 4;            // k-slice: channels kq*8..+7

    // ---- weights -> register A-fragments ----
    short8 bfr[2][9];
#pragma unroll
    for (int h = 0; h < 2; ++h) {
        const float* wf = w + (h * 16 + fcol) * 288 + kq * 8;
#pragma unroll
        for (int s = 0; s < 9; ++s) {
            float4 lo = reinterpret_cast<const float4*>(wf + s * 32)[0];
            float4 hi = reinterpret_cast<const float4*>(wf + s * 32)[1];
            short8 v;
            v[0] = f2bf(lo.x); v[1] = f2bf(lo.y); v[2] = f2bf(lo.z); v[3] = f2bf(lo.w);
            v[4] = f2bf(hi.x); v[5] = f2bf(hi.y); v[6] = f2bf(hi.z); v[7] = f2bf(hi.w);
            bfr[h][s] = v;
        }
    }
    const float4 bias0 = reinterpret_cast<const float4*>(bias)[kq];
    const float4 bias1 = reinterpret_cast<const float4*>(bias)[4 + kq];

    // ---- work decode, XCD-bijective (256 = 8 x 32): each XCD owns 2 images ----
    const int bid  = blockIdx.x;
    const int sbid = (bid & 7) * 32 + (bid >> 3);
    const int W    = sbid * 8 + wave;      // 0..2047 wave-strip id
    const int b    = W >> 7;               // image (128 strips each)
    const int rem  = W & 127;
    const int cst  = rem >> 5;             // col strip 0..3
    const int rst  = rem & 31;             // row strip 0..31
    const int c0   = cst * 64;
    const int gr0  = rst * RPW;
    const int nck  = (cst < 3) ? 4 : 2;    // strip 3: cols 192..221 -> 2 chunks

    // two NAMED stage register sets (static parity; never addressable)
    float4 svA[NSG], svB[NSG];

#define SLOAD(RR, SET)                                                        \
    {                                                                         \
        int ir_ = gr0 + (RR); if (ir_ > HIN - 1) ir_ = HIN - 1;               \
        _Pragma("unroll")                                                     \
        for (int i_ = 0; i_ < NSG; ++i_) {                                    \
            int g_ = lane + 64 * i_; if (g_ > 527) g_ = 527;                  \
            int px_ = g_ >> 3, sub_ = g_ & 7;                                 \
            int ic_ = c0 + px_; if (ic_ > WIN - 1) ic_ = WIN - 1;             \
            sv##SET[i_] = *reinterpret_cast<const float4*>(                   \
                x + ((b * HIN + ir_) * WIN + ic_) * CIN + sub_ * 4);          \
        }                                                                     \
    }

#define SWRITE(RR, SET)                                                       \
    {                                                                         \
        char* sb_ = wbase + ((RR) & 3) * WROWB;                               \
        _Pragma("unroll")                                                     \
        for (int i_ = 0; i_ < NSG; ++i_) {                                    \
            int g_ = lane + 64 * i_; if (g_ > 527) g_ = 527;                  \
            int px_ = g_ >> 3, sub_ = g_ & 7;                                 \
            uint4 u_ = __builtin_bit_cast(uint4, sv##SET[i_]);                \
            uint2 p_;                                                         \
            p_.x = __builtin_amdgcn_perm(u_.y, u_.x, 0x07060302u);            \
            p_.y = __builtin_amdgcn_perm(u_.w, u_.z, 0x07060302u);            \
            *reinterpret_cast<uint2*>(sb_ + px_ * 64 + sub_ * 8) = p_;        \
        }                                                                     \
    }

#define COMPUTE(R)                                                            \
    {                                                                         \
        const int ho_ = gr0 + (R);                                            \
        _Pragma("unroll")                                                     \
        for (int ck_ = 0; ck_ < 4; ++ck_) {                                   \
            if (ck_ < nck) {                                                  \
                float4v a0_ = {0.f, 0.f, 0.f, 0.f};                           \
                float4v a1_ = {0.f, 0.f, 0.f, 0.f};                           \
                _Pragma("unroll")                                             \
                for (int s_ = 0; s_ < 9; ++s_) {                              \
                    const int kh_ = s_ / 3, kw_ = s_ % 3;                     \
                    const short8 a_ = *reinterpret_cast<const short8*>(       \
                        wbase + (((R) + kh_) & 3) * WROWB +                   \
                        (ck_ * 16 + fcol + kw_) * 64 + kq * 16);              \
                    a0_ = __builtin_amdgcn_mfma_f32_16x16x32_bf16(            \
                        bfr[0][s_], a_, a0_, 0, 0, 0);                        \
                    a1_ = __builtin_amdgcn_mfma_f32_16x16x32_bf16(            \
                        bfr[1][s_], a_, a1_, 0, 0, 0);                        \
                }                                                             \
                const int wo_ = c0 + ck_ * 16 + fcol;                         \
                if (ho_ < HO && wo_ < WO) {                                   \
                    float* o_ = out + ((b * HO + ho_) * WO + wo_) * FOUT;     \
                    float4 v0_ = {a0_[0] + bias0.x, a0_[1] + bias0.y,         \
                                  a0_[2] + bias0.z, a0_[3] + bias0.w};        \
                    float4 v1_ = {a1_[0] + bias1.x, a1_[1] + bias1.y,         \
                                  a1_[2] + bias1.z, a1_[3] + bias1.w};        \
                    reinterpret_cast<float4*>(o_)[kq]     = v0_;              \
                    reinterpret_cast<float4*>(o_)[4 + kq] = v1_;              \
                }                                                             \
            }                                                                 \
        }                                                                     \
    }

#define SB __builtin_amdgcn_sched_barrier(0)

    // ---------- prologue: rows 0..3; parity = row&1 (even->A, odd->B) ----------
    SLOAD(0, A); SLOAD(1, B);
    SWRITE(0, A); SWRITE(1, B);
    SLOAD(2, A); SLOAD(3, B);
    SWRITE(2, A);
    // live: svA free (W2 done), svB = row 3 (written at end of iter 0)

    // ---------- main loop, manual x2 unroll for static reg-set parity ----------
#pragma unroll 1
    for (int r = 0; r < RPW; r += 2) {
        // ---- even iter r: load->A, write<-B ----
        if (r + 4 <= RPW + 1) SLOAD(r + 4, A);   // rows 4,6,8 (even)
        SB;
        COMPUTE(r);
        SB;
        if (r + 3 <= RPW + 1) SWRITE(r + 3, B);  // rows 3,5,7 (odd)
        SB;
        // ---- odd iter r+1: load->B, write<-A ----
        if (r + 1 < RPW) {
            if (r + 5 <= RPW + 1) SLOAD(r + 5, B);   // rows 5,7 (odd)
            SB;
            COMPUTE(r + 1);
            SB;
            if (r + 4 <= RPW + 1) SWRITE(r + 4, A);  // rows 4,6,8 (even)
            SB;
        }
    }
#undef SLOAD
#undef SWRITE
#undef COMPUTE
#undef SB
}

extern "C" void kernel_launch(void* const* d_in, const int* in_sizes, int n_in,
                              void* d_out, int out_size, void* d_ws, size_t ws_size,
                              hipStream_t stream) {
    const float* x    = (const float*)d_in[0];
    const float* w    = (const float*)d_in[1];
    const float* bias = (const float*)d_in[2];
    float* out        = (float*)d_out;

    conv3x3_wave<<<dim3(256), dim3(512), 0, stream>>>(x, w, bias, out);
}